// Round 7
// baseline (754.645 us; speedup 1.0000x reference)
//
#include <hip/hip_runtime.h>
#include <hip/hip_bf16.h>
#include <math.h>

// Problem constants
#define B_  4
#define S_  2048
#define D_  512
#define H_  8
#define DH_ 64
#define FF_ 2048
#define L_  4
#define V_  256
#define NTOK (B_ * S_)          // 8192
#define XN  ((size_t)NTOK * D_) // 4,194,304 elems per [B,S,D] buffer

typedef __attribute__((ext_vector_type(8))) short bf16x8;
typedef __attribute__((ext_vector_type(4))) float f32x4;
typedef __attribute__((ext_vector_type(8))) unsigned short u16x8;
typedef __attribute__((ext_vector_type(4))) unsigned short u16x4;

typedef const __attribute__((address_space(1))) unsigned int* gptr_u32;
typedef __attribute__((address_space(3))) unsigned int* lptr_u32;

__device__ __forceinline__ float bf2f(unsigned short u) {
    return __uint_as_float((unsigned)u << 16);
}
__device__ __forceinline__ unsigned short f2bf_bits(float f) {
    __hip_bfloat16 t = __float2bfloat16(f);
    return *(unsigned short*)&t;
}

// ---------------------------------------------------------------------------
// Positional-encoding table: PE[s][d], computed once per launch.
// ---------------------------------------------------------------------------
__global__ void pe_table_kernel(float* __restrict__ PE) {
    int s = blockIdx.x;
    int d = threadIdx.x * 2;              // 256 threads -> d = 0,2,...,510
    float ang = (float)s * expf((float)d * (-logf(10000.0f) / (float)D_));
    PE[(size_t)s * D_ + d]     = sinf(ang);
    PE[(size_t)s * D_ + d + 1] = cosf(ang);
}

// ---------------------------------------------------------------------------
// Embedding + PE lookup -> X fp32 and Xb bf16. grid NTOK, 128 threads.
// ---------------------------------------------------------------------------
__global__ void embed_kernel(const int* __restrict__ tok,
                             const float* __restrict__ emb,
                             const float* __restrict__ PE,
                             float* __restrict__ X,
                             __hip_bfloat16* __restrict__ Xb) {
    int bs = blockIdx.x;
    int s = bs % S_;
    int t = tok[bs];
    const float scale = 22.62741699796952f; // sqrt(512)
    int d = threadIdx.x * 4;
    float4 e = *(const float4*)(emb + (size_t)t * D_ + d);
    float4 p = *(const float4*)(PE + (size_t)s * D_ + d);
    float4 v = make_float4(e.x * scale + p.x, e.y * scale + p.y,
                           e.z * scale + p.z, e.w * scale + p.w);
    *(float4*)(X + (size_t)bs * D_ + d) = v;
    u16x4 pk = { f2bf_bits(v.x), f2bf_bits(v.y), f2bf_bits(v.z), f2bf_bits(v.w) };
    *(u16x4*)((unsigned short*)Xb + (size_t)bs * D_ + d) = pk;
}

// ---------------------------------------------------------------------------
// Weight prep
// ---------------------------------------------------------------------------
__global__ void transpose_conv_kernel(const float* __restrict__ W,
                                      __hip_bfloat16* __restrict__ Wt,
                                      int K, int N) {
    const float* Wl = W + (size_t)blockIdx.z * K * N;
    __hip_bfloat16* Wtl = Wt + (size_t)blockIdx.z * K * N;
    __shared__ float t[32][33];
    int k0 = blockIdx.y * 32, n0 = blockIdx.x * 32;
    int tx = threadIdx.x & 31, ty = threadIdx.x >> 5;
    #pragma unroll
    for (int q = 0; q < 4; ++q)
        t[ty + q * 8][tx] = Wl[(size_t)(k0 + ty + q * 8) * N + n0 + tx];
    __syncthreads();
    #pragma unroll
    for (int q = 0; q < 4; ++q)
        Wtl[(size_t)(n0 + ty + q * 8) * K + k0 + tx] =
            __float2bfloat16(t[tx][ty + q * 8]);
}

// QKV fused: dst[l][1536][512], rows 0-511 Wq^T, 512-1023 Wk^T, 1024-1535 Wv^T
__global__ void transpose_qkv_kernel(const float* __restrict__ Wq,
                                     const float* __restrict__ Wk,
                                     const float* __restrict__ Wv,
                                     __hip_bfloat16* __restrict__ dst) {
    int z = blockIdx.z, l = z / 3, which = z % 3;
    const float* src = (which == 0 ? Wq : which == 1 ? Wk : Wv) + (size_t)l * D_ * D_;
    __hip_bfloat16* d = dst + (size_t)l * 1536 * D_ + (size_t)which * D_ * D_;
    __shared__ float t[32][33];
    int k0 = blockIdx.y * 32, n0 = blockIdx.x * 32;
    int tx = threadIdx.x & 31, ty = threadIdx.x >> 5;
    #pragma unroll
    for (int q = 0; q < 4; ++q)
        t[ty + q * 8][tx] = src[(size_t)(k0 + ty + q * 8) * D_ + n0 + tx];
    __syncthreads();
    #pragma unroll
    for (int q = 0; q < 4; ++q)
        d[(size_t)(n0 + ty + q * 8) * D_ + k0 + tx] =
            __float2bfloat16(t[tx][ty + q * 8]);
}

__global__ void conv_bf16_kernel(const float* __restrict__ in,
                                 __hip_bfloat16* __restrict__ out, int n) {
    int i = blockIdx.x * 256 + threadIdx.x;
    if (i < n) out[i] = __float2bfloat16(in[i]);
}

// ---------------------------------------------------------------------------
// bf16 MFMA GEMM, double-buffered: C = A[M,K] @ Bt[N,K]^T + bias
// BM = 128 or 64. BN=128, BK=32. Counted vmcnt keeps next tile's
// global_load_lds in flight across the barrier.
// OUT_MODE: 0 = fp32 [M,N]; 1 = bf16 [M,N]; 4 = QKV fused (N=1536)
// ---------------------------------------------------------------------------
template <int BM, int RELU, int OUT_MODE>
__global__ __launch_bounds__(256)
void gemm_bf16_kernel(const __hip_bfloat16* __restrict__ A,
                      const __hip_bfloat16* __restrict__ Bt,
                      const float* __restrict__ bias0,
                      const float* __restrict__ bias1,
                      const float* __restrict__ bias2,
                      float* __restrict__ Cf,
                      __hip_bfloat16* __restrict__ Cb0,
                      __hip_bfloat16* __restrict__ Cb1,
                      __hip_bfloat16* __restrict__ Cb2,
                      __hip_bfloat16* __restrict__ CbT,
                      int M, int N, int K) {
    constexpr int MI = BM / 32;              // M-fragments per wave
    __shared__ unsigned short As[2][BM * 32];
    __shared__ unsigned short Bs[2][128 * 32];
    int tid = threadIdx.x;
    int lane = tid & 63, wid = tid >> 6;
    int wm = (wid >> 1) * (BM / 2), wn = (wid & 1) * 64;
    int g = lane >> 4, il = lane & 15;

    // XCD-aware swizzle: contiguous chunk of flat ids per XCD (grid % 8 == 0)
    int gx = gridDim.x;
    int fid = blockIdx.x + gx * blockIdx.y;
    int cpx = (gx * gridDim.y) >> 3;
    int swz = (fid & 7) * cpx + (fid >> 3);
    int m0 = (swz / gx) * BM, n0 = (swz % gx) * 128;

    auto stage = [&](int buf, int k0) {
        #pragma unroll
        for (int q = 0; q < BM / 64; ++q) {
            int idx = q * 256 + tid;
            int r = idx >> 2, c = idx & 3;
            int csw = (c ^ r) & 3;
            const __hip_bfloat16* sa = A + (size_t)(m0 + r) * K + k0 + csw * 8;
            __builtin_amdgcn_global_load_lds((gptr_u32)(const void*)sa,
                                             (lptr_u32)(void*)&As[buf][idx * 8], 16, 0, 0);
        }
        #pragma unroll
        for (int q = 0; q < 2; ++q) {
            int idx = q * 256 + tid;
            int r = idx >> 2, c = idx & 3;
            int csw = (c ^ r) & 3;
            const __hip_bfloat16* sb = Bt + (size_t)(n0 + r) * K + k0 + csw * 8;
            __builtin_amdgcn_global_load_lds((gptr_u32)(const void*)sb,
                                             (lptr_u32)(void*)&Bs[buf][idx * 8], 16, 0, 0);
        }
    };

    f32x4 acc[MI][4] = {};
    int NT = K >> 5;
    stage(0, 0);

    for (int t = 0; t < NT; ++t) {
        int cur = t & 1;
        if (t + 1 < NT) {
            stage(cur ^ 1, (t + 1) << 5);
            if constexpr (BM == 128)
                asm volatile("s_waitcnt vmcnt(4)" ::: "memory");
            else
                asm volatile("s_waitcnt vmcnt(3)" ::: "memory");
        } else {
            asm volatile("s_waitcnt vmcnt(0)" ::: "memory");
        }
        __builtin_amdgcn_s_barrier();

        bf16x8 af[MI], bf[4];
        #pragma unroll
        for (int i = 0; i < MI; ++i) {
            int m = wm + i * 16 + il;
            af[i] = *(const bf16x8*)&As[cur][m * 32 + ((g ^ m) & 3) * 8];
        }
        #pragma unroll
        for (int j = 0; j < 4; ++j) {
            int n = wn + j * 16 + il;
            bf[j] = *(const bf16x8*)&Bs[cur][n * 32 + ((g ^ n) & 3) * 8];
        }
        #pragma unroll
        for (int i = 0; i < MI; ++i)
            #pragma unroll
            for (int j = 0; j < 4; ++j)
                acc[i][j] = __builtin_amdgcn_mfma_f32_16x16x32_bf16(
                    af[i], bf[j], acc[i][j], 0, 0, 0);

        __builtin_amdgcn_s_barrier();   // all waves done reading before overwrite
    }

    // C/D layout: col = lane&15, row = (lane>>4)*4 + reg
    if constexpr (OUT_MODE == 4) {
        int seg = n0 >> 9;                       // block-uniform
        const float* bias = seg == 0 ? bias0 : seg == 1 ? bias1 : bias2;
        __hip_bfloat16* Crow = seg == 0 ? Cb0 : seg == 1 ? Cb1 : Cb2;
        int nseg = n0 & 511;
        #pragma unroll
        for (int j = 0; j < 4; ++j) {
            int coll = nseg + wn + j * 16 + il;
            float bv = bias[coll];
            #pragma unroll
            for (int i = 0; i < MI; ++i) {
                int row0 = m0 + wm + i * 16 + g * 4;
                if (seg < 2) {
                    #pragma unroll
                    for (int r = 0; r < 4; ++r)
                        Crow[(size_t)(row0 + r) * 512 + coll] =
                            __float2bfloat16(acc[i][j][r] + bv);
                } else {
                    u16x4 pk;
                    #pragma unroll
                    for (int r = 0; r < 4; ++r) {
                        float v = acc[i][j][r] + bv;
                        Crow[(size_t)(row0 + r) * 512 + coll] = __float2bfloat16(v);
                        pk[r] = f2bf_bits(v);
                    }
                    int hh = coll >> 6, dh = coll & 63;
                    int bb = row0 >> 11, s0 = row0 & 2047;
                    *(u16x4*)(CbT + ((size_t)((bb * 8 + hh) * 64 + dh) * 2048 + s0)) = pk;
                }
            }
        }
    } else {
        #pragma unroll
        for (int j = 0; j < 4; ++j) {
            int col = n0 + wn + j * 16 + il;
            float bv = bias0[col];
            #pragma unroll
            for (int i = 0; i < MI; ++i) {
                #pragma unroll
                for (int r = 0; r < 4; ++r) {
                    int row = m0 + wm + i * 16 + g * 4 + r;
                    float v = acc[i][j][r] + bv;
                    if (RELU) v = fmaxf(v, 0.0f);
                    if (OUT_MODE == 1) Cb0[(size_t)row * N + col] = __float2bfloat16(v);
                    else               Cf[(size_t)row * N + col] = v;
                }
            }
        }
    }
}

// ---------------------------------------------------------------------------
// MFMA block-sparse flash attention (v4: work-paired + balanced dispatch).
// Each block processes TWO q-tiles: qt*64 and (31-qt)*64 -> near-uniform work
// (tiles 7..12 per block). qt bit-reversed across dispatch so heavy/light
// blocks interleave on CUs. (b,h) groups cluster per XCD (K/V L2 reuse).
// Strided keys: fixed 13-slot unrolled two-pass (dots -> softmax -> PV),
// masked by clamped loads -> no serial load/exp chain.
// ---------------------------------------------------------------------------
__device__ __forceinline__ bf16x8 lds_frag(const unsigned short* base, int row, int chunk) {
    int byte = (row << 7) + (((chunk ^ (row & 7)) & 7) << 4);
    return *(const bf16x8*)((const char*)base + byte);
}

__global__ __launch_bounds__(256)
void attn_mfma_kernel(const __hip_bfloat16* __restrict__ Q,   // [NTOK][512]
                      const __hip_bfloat16* __restrict__ K,   // [NTOK][512]
                      const __hip_bfloat16* __restrict__ V,   // [NTOK][512]
                      const __hip_bfloat16* __restrict__ VT,  // [B*H*64][2048]
                      __hip_bfloat16* __restrict__ O) {       // [NTOK][512]
    __shared__ unsigned short Ks[2][64 * 64];
    __shared__ unsigned short Vs[2][64 * 64];
    __shared__ unsigned short Ps[4][16 * 64];

    // balanced dispatch map: d -> (qt via bit-reverse, (b,h) clustered per XCD)
    int d = blockIdx.x + 16 * (blockIdx.y + 8 * blockIdx.z);  // 0..511
    int xcd = d & 7, t8 = d >> 3;
    int qtr = t8 & 15, gsub = t8 >> 4;                        // gsub 0..3
    int qt = ((qtr & 1) << 3) | ((qtr & 2) << 1) | ((qtr & 4) >> 1) | ((qtr & 8) >> 3);
    int grp = xcd * 4 + gsub;                                 // 0..31
    int h = grp & 7, b = grp >> 3;

    int tid = threadIdx.x, lane = tid & 63, wv = tid >> 6;
    int g = lane >> 4, il = lane & 15, g4 = g * 4;

    const size_t vt_off = (size_t)((b * 8 + h) * 64) * 2048;
    const unsigned short* Kbase = (const unsigned short*)(K + (size_t)b * 2048 * 512 + h * 64);
    const unsigned short* Vbase = (const unsigned short*)(V + (size_t)b * 2048 * 512 + h * 64);
    const float CSC = 0.18033688011112042f; // 0.125 * log2(e)

    auto stage = [&](int buf, int j0) {
        #pragma unroll
        for (int q = 0; q < 2; ++q) {
            int idx = q * 256 + tid;
            int row = idx >> 3, c = idx & 7;
            int csw = c ^ (row & 7);
            const __hip_bfloat16* sk = K + (size_t)(b * 2048 + j0 + row) * 512 + h * 64 + csw * 8;
            __builtin_amdgcn_global_load_lds((gptr_u32)(const void*)sk,
                                             (lptr_u32)(void*)&Ks[buf][idx * 8], 16, 0, 0);
            const __hip_bfloat16* sv = VT + vt_off + (size_t)row * 2048 + j0 + csw * 8;
            __builtin_amdgcn_global_load_lds((gptr_u32)(const void*)sv,
                                             (lptr_u32)(void*)&Vs[buf][idx * 8], 16, 0, 0);
        }
    };

    unsigned short* myP = Ps[wv];

    #pragma unroll 1
    for (int half = 0; half < 2; ++half) {
        int i0 = (half == 0) ? qt * 64 : (31 - qt) * 64;
        int nloc = min(i0 >> 6, 4) + 1;
        int add0 = (i0 > 256);
        int nt = nloc + add0;
        auto j0_of = [&](int t) { return (t < nloc) ? (i0 - 64 * t) : 0; };

        __syncthreads();                 // epilogue scratch (Ks) free before restage
        stage(0, i0);                    // first tile prefetch, overlaps scalar phase

        int iq = i0 + wv * 16 + il;
        bf16x8 qf[2];
        #pragma unroll
        for (int kh = 0; kh < 2; ++kh)
            qf[kh] = *(const bf16x8*)(Q + (size_t)(b * 2048 + iq) * 512 + h * 64 + kh * 32 + g * 8);
        float qfl[16];
        #pragma unroll
        for (int kh = 0; kh < 2; ++kh)
            #pragma unroll
            for (int e = 0; e < 8; ++e)
                qfl[kh * 8 + e] = bf2f(((u16x8)qf[kh])[e]);

        f32x4 o[4] = {};
        float os[16] = {};
        float m = -1e30f, l = 0.0f;

        // ---- strided phase: fixed 13-slot two-pass, masked ----
        int nst = (iq >= 400) ? ((iq - 400) >> 7) + 1 : 0;
        if (nst > 0) {
            float sarr[13];
            #pragma unroll
            for (int mm = 0; mm < 13; ++mm) {
                int j = iq - 384 - 128 * mm;
                int jc = (j >= 16) ? j : 16;
                const unsigned short* kr = Kbase + (size_t)jc * 512;
                u16x8 k0 = *(const u16x8*)(kr + g * 8);
                u16x8 k1 = *(const u16x8*)(kr + 32 + g * 8);
                float dot = 0.0f;
                #pragma unroll
                for (int e = 0; e < 8; ++e)
                    dot += qfl[e] * bf2f(k0[e]) + qfl[8 + e] * bf2f(k1[e]);
                dot += __shfl_xor(dot, 16);
                dot += __shfl_xor(dot, 32);
                sarr[mm] = (j >= 16) ? dot * CSC : -1e30f;
            }
            float mmax = -1e30f;
            #pragma unroll
            for (int mm = 0; mm < 13; ++mm) mmax = fmaxf(mmax, sarr[mm]);
            float p[13];
            float lsum = 0.0f;
            #pragma unroll
            for (int mm = 0; mm < 13; ++mm) {
                p[mm] = exp2f(sarr[mm] - mmax);
                lsum += p[mm];
            }
            #pragma unroll
            for (int mm = 0; mm < 13; ++mm) {
                int j = iq - 384 - 128 * mm;
                int jc = (j >= 16) ? j : 16;
                const unsigned short* vr = Vbase + (size_t)jc * 512;
                u16x8 v0 = *(const u16x8*)(vr + g * 8);
                u16x8 v1 = *(const u16x8*)(vr + 32 + g * 8);
                #pragma unroll
                for (int e = 0; e < 8; ++e) {
                    os[e]     += p[mm] * bf2f(v0[e]);
                    os[8 + e] += p[mm] * bf2f(v1[e]);
                }
            }
            m = mmax;
            l = lsum;
        }

        // ---- MFMA tile phase ----
        for (int t = 0; t < nt; ++t) {
            __syncthreads();
            int cur = t & 1;
            if (t + 1 < nt) stage(cur ^ 1, j0_of(t + 1));
            int j0 = j0_of(t);
            bool gtile = (t >= nloc);
            bool dtile = (t == 0);

            f32x4 s[4] = {};
            __builtin_amdgcn_s_setprio(1);
            if (gtile) {
                #pragma unroll
                for (int kh = 0; kh < 2; ++kh) {
                    bf16x8 a = lds_frag(Ks[cur], il, kh * 4 + g);
                    s[0] = __builtin_amdgcn_mfma_f32_16x16x32_bf16(a, qf[kh], s[0], 0, 0, 0);
                }
            } else if (dtile) {
                #pragma unroll
                for (int kh = 0; kh < 2; ++kh)
                    #pragma unroll
                    for (int jn = 0; jn < 4; ++jn)
                        if (jn <= wv) {
                            bf16x8 a = lds_frag(Ks[cur], jn * 16 + il, kh * 4 + g);
                            s[jn] = __builtin_amdgcn_mfma_f32_16x16x32_bf16(a, qf[kh], s[jn], 0, 0, 0);
                        }
            } else {
                #pragma unroll
                for (int kh = 0; kh < 2; ++kh)
                    #pragma unroll
                    for (int jn = 0; jn < 4; ++jn) {
                        bf16x8 a = lds_frag(Ks[cur], jn * 16 + il, kh * 4 + g);
                        s[jn] = __builtin_amdgcn_mfma_f32_16x16x32_bf16(a, qf[kh], s[jn], 0, 0, 0);
                    }
            }
            __builtin_amdgcn_s_setprio(0);

            // scale + mask + local max
            float mloc = -1e30f;
            if (gtile) {
                #pragma unroll
                for (int r = 0; r < 4; ++r) {
                    float sv = s[0][r] * CSC;
                    s[0][r] = sv;
                    mloc = fmaxf(mloc, sv);
                }
            } else if (dtile) {
                #pragma unroll
                for (int jn = 0; jn < 4; ++jn) {
                    if (jn < wv) {
                        #pragma unroll
                        for (int r = 0; r < 4; ++r) {
                            float sv = s[jn][r] * CSC;
                            s[jn][r] = sv;
                            mloc = fmaxf(mloc, sv);
                        }
                    } else if (jn == wv) {
                        #pragma unroll
                        for (int r = 0; r < 4; ++r) {
                            float sv = (g4 + r <= il) ? s[jn][r] * CSC : -1e30f;
                            s[jn][r] = sv;
                            mloc = fmaxf(mloc, sv);
                        }
                    }
                }
            } else if (t == 4) {       // window edge: local | strided | global
                #pragma unroll
                for (int jn = 0; jn < 4; ++jn)
                    #pragma unroll
                    for (int r = 0; r < 4; ++r) {
                        int jg = j0 + jn * 16 + g4 + r;
                        int dij = iq - jg;
                        bool ok = (dij < 256) || ((dij & 127) == 0) || (jg < 16);
                        float sv = ok ? s[jn][r] * CSC : -1e30f;
                        s[jn][r] = sv;
                        mloc = fmaxf(mloc, sv);
                    }
            } else {
                #pragma unroll
                for (int jn = 0; jn < 4; ++jn)
                    #pragma unroll
                    for (int r = 0; r < 4; ++r) {
                        float sv = s[jn][r] * CSC;
                        s[jn][r] = sv;
                        mloc = fmaxf(mloc, sv);
                    }
            }
            mloc = fmaxf(mloc, __shfl_xor(mloc, 16));
            mloc = fmaxf(mloc, __shfl_xor(mloc, 32));
            float mn = fmaxf(m, mloc);
            float al = exp2f(m - mn);

            float lloc = 0.0f;
            if (gtile) {
                #pragma unroll
                for (int r = 0; r < 4; ++r) {
                    float p = exp2f(s[0][r] - mn);
                    s[0][r] = p;
                    lloc += p;
                }
            } else {
                #pragma unroll
                for (int jn = 0; jn < 4; ++jn) {
                    if (dtile && jn > wv) continue;
                    #pragma unroll
                    for (int r = 0; r < 4; ++r) {
                        float p = exp2f(s[jn][r] - mn);
                        s[jn][r] = p;
                        lloc += p;
                    }
                }
            }
            lloc += __shfl_xor(lloc, 16);
            lloc += __shfl_xor(lloc, 32);
            l = l * al + lloc;
            m = mn;

            if (!__all(al == 1.0f)) {
                float ar[4];
                #pragma unroll
                for (int r = 0; r < 4; ++r) ar[r] = __shfl(al, g4 + r);
                #pragma unroll
                for (int dn = 0; dn < 4; ++dn)
                    #pragma unroll
                    for (int r = 0; r < 4; ++r) o[dn][r] *= ar[r];
                #pragma unroll
                for (int e = 0; e < 16; ++e) os[e] *= al;
            }

            // P -> LDS (gtile: jn0 data + jn1 zeros; dtile: zeros for jn>wv)
            #pragma unroll
            for (int jn = 0; jn < 4; ++jn) {
                if (gtile && jn >= 2) continue;
                u16x4 pk = { 0, 0, 0, 0 };
                bool live = gtile ? (jn == 0) : (!dtile || jn <= wv);
                if (live) {
                    #pragma unroll
                    for (int r = 0; r < 4; ++r) pk[r] = f2bf_bits(s[jn][r]);
                }
                int byte = ((il << 7) + (jn << 5) + (g << 3)) ^ ((il & 7) << 4);
                *(u16x4*)((char*)myP + byte) = pk;
            }
            int khmax = (gtile || (dtile && wv < 2)) ? 1 : 2;
            __builtin_amdgcn_s_setprio(1);
            #pragma unroll
            for (int kh = 0; kh < 2; ++kh) {
                if (kh < khmax) {
                    bf16x8 pa = lds_frag(myP, il, kh * 4 + g);
                    #pragma unroll
                    for (int dn = 0; dn < 4; ++dn) {
                        bf16x8 bv = lds_frag(Vs[cur], dn * 16 + il, kh * 4 + g);
                        o[dn] = __builtin_amdgcn_mfma_f32_16x16x32_bf16(pa, bv, o[dn], 0, 0, 0);
                    }
                }
            }
            __builtin_amdgcn_s_setprio(0);
        }

        // ---- epilogue: merge os (row=il, dim split by g) with o fragment ----
        __syncthreads();
        float* osl = (float*)&Ks[0][0] + wv * 1024;  // spans Ks[0..1]: 16KB
        #pragma unroll
        for (int kh = 0; kh < 2; ++kh)
            #pragma unroll
            for (int e = 0; e < 8; ++e)
                osl[il * 64 + kh * 32 + g * 8 + e] = os[kh * 8 + e];
        __syncthreads();

        float li[4];
        #pragma unroll
        for (int r = 0; r < 4; ++r) li[r] = 1.0f / __shfl(l, g4 + r);
        #pragma unroll
        for (int dn = 0; dn < 4; ++dn)
            #pragma unroll
            for (int r = 0; r < 4; ++r) {
                int row = i0 + wv * 16 + g4 + r;
                float add = osl[(g4 + r) * 64 + dn * 16 + il];
                O[(size_t)(b * 2048 + row) * 512 + h * 64 + dn * 16 + il] =
                    __float2bfloat16((o[dn][r] + add) * li[r]);
            }
    }
}

// ---------------------------------------------------------------------------
// Fused residual add + LayerNorm, vectorized: 4 rows/block (4 waves)
// ---------------------------------------------------------------------------
__global__ __launch_bounds__(256)
void add_ln_kernel(float* __restrict__ X,
                   const __hip_bfloat16* __restrict__ T,
                   const float* __restrict__ g,
                   const float* __restrict__ bb,
                   __hip_bfloat16* __restrict__ Xb) {
    size_t row = blockIdx.x * 4 + (threadIdx.x >> 6);
    int lane = threadIdx.x & 63;
    int d0 = lane * 8;
    float4 x0 = *(const float4*)(X + row * D_ + d0);
    float4 x1 = *(const float4*)(X + row * D_ + d0 + 4);
    u16x8 tv = *(const u16x8*)((const unsigned short*)T + row * D_ + d0);
    float v[8] = { x0.x + bf2f(tv[0]), x0.y + bf2f(tv[1]),
                   x0.z + bf2f(tv[2]), x0.w + bf2f(tv[3]),
                   x1.x + bf2f(tv[4]), x1.y + bf2f(tv[5]),
                   x1.z + bf2f(tv[6]), x1.w + bf2f(tv[7]) };
    float sum = 0.0f;
    #pragma unroll
    for (int q = 0; q < 8; ++q) sum += v[q];
    #pragma unroll
    for (int o = 32; o; o >>= 1) sum += __shfl_xor(sum, o);
    float mean = sum * (1.0f / D_);
    float var = 0.0f;
    #pragma unroll
    for (int q = 0; q < 8; ++q) { float dd = v[q] - mean; var += dd * dd; }
    #pragma unroll
    for (int o = 32; o; o >>= 1) var += __shfl_xor(var, o);
    var *= (1.0f / D_);
    float r = rsqrtf(var + 1e-5f);
    float4 g0 = *(const float4*)(g + d0),  g1 = *(const float4*)(g + d0 + 4);
    float4 b0 = *(const float4*)(bb + d0), b1 = *(const float4*)(bb + d0 + 4);
    float y[8];
    y[0] = (v[0]-mean)*r*g0.x+b0.x; y[1] = (v[1]-mean)*r*g0.y+b0.y;
    y[2] = (v[2]-mean)*r*g0.z+b0.z; y[3] = (v[3]-mean)*r*g0.w+b0.w;
    y[4] = (v[4]-mean)*r*g1.x+b1.x; y[5] = (v[5]-mean)*r*g1.y+b1.y;
    y[6] = (v[6]-mean)*r*g1.z+b1.z; y[7] = (v[7]-mean)*r*g1.w+b1.w;
    *(float4*)(X + row * D_ + d0)     = make_float4(y[0], y[1], y[2], y[3]);
    *(float4*)(X + row * D_ + d0 + 4) = make_float4(y[4], y[5], y[6], y[7]);
    u16x8 pk;
    #pragma unroll
    for (int q = 0; q < 8; ++q) pk[q] = f2bf_bits(y[q]);
    *(u16x8*)((unsigned short*)Xb + row * D_ + d0) = pk;
}

// ---------------------------------------------------------------------------
extern "C" void kernel_launch(void* const* d_in, const int* in_sizes, int n_in,
                              void* d_out, int out_size, void* d_ws, size_t ws_size,
                              hipStream_t stream) {
    const int*   tok   = (const int*)  d_in[0];
    const float* emb   = (const float*)d_in[1];
    const float* b_out = (const float*)d_in[2];
    const float* Wq    = (const float*)d_in[3];
    const float* bq    = (const float*)d_in[4];
    const float* Wk    = (const float*)d_in[5];
    const float* bk    = (const float*)d_in[6];
    const float* Wv    = (const float*)d_in[7];
    const float* bv    = (const float*)d_in[8];
    const float* Wo    = (const float*)d_in[9];
    const float* bo    = (const float*)d_in[10];
    const float* ln1g  = (const float*)d_in[11];
    const float* ln1b  = (const float*)d_in[12];
    const float* W1    = (const float*)d_in[13];
    const float* b1    = (const float*)d_in[14];
    const float* W2    = (const float*)d_in[15];
    const float* b2    = (const float*)d_in[16];
    const float* ln2g  = (const float*)d_in[17];
    const float* ln2b  = (const float*)d_in[18];
    float* out = (float*)d_out;

    char* w = (char*)d_ws;
    auto alloc = [&](size_t bytes) {
        char* p = w;
        w += (bytes + 255) & ~(size_t)255;
        return p;
    };
    float*          X   = (float*)         alloc(XN * 4);
    __hip_bfloat16* Xb  = (__hip_bfloat16*)alloc(XN * 2);
    __hip_bfloat16* Tb  = (__hip_bfloat16*)alloc(XN * 2);
    char* uni = alloc(XN * 2 * 5);
    __hip_bfloat16* Qb  = (__hip_bfloat16*)uni;
    __hip_bfloat16* Kb  = Qb + XN;
    __hip_bfloat16* Vb  = Kb + XN;
    __hip_bfloat16* VTb = Vb + XN;   // [B,H,64,S]
    __hip_bfloat16* Ob  = VTb + XN;
    __hip_bfloat16* Hb  = (__hip_bfloat16*)uni;      // [NTOK, FF] (reuses Qb..VTb)
    __hip_bfloat16* Wqkvt = (__hip_bfloat16*)alloc((size_t)L_ * 1536 * D_ * 2);
    __hip_bfloat16* Wot  = (__hip_bfloat16*)alloc((size_t)L_ * D_ * D_ * 2);
    __hip_bfloat16* W1t  = (__hip_bfloat16*)alloc((size_t)L_ * D_ * FF_ * 2);
    __hip_bfloat16* W2t  = (__hip_bfloat16*)alloc((size_t)L_ * FF_ * D_ * 2);
    __hip_bfloat16* embb = (__hip_bfloat16*)alloc((size_t)V_ * D_ * 2);
    float*          PE   = (float*)alloc((size_t)S_ * D_ * 4);

    // ---- prep ----
    {
        pe_table_kernel<<<S_, 256, 0, stream>>>(PE);
        dim3 gqkv(D_ / 32, D_ / 32, L_ * 3);
        transpose_qkv_kernel<<<gqkv, 256, 0, stream>>>(Wq, Wk, Wv, Wqkvt);
        dim3 gdd(D_ / 32, D_ / 32, L_);
        transpose_conv_kernel<<<gdd, 256, 0, stream>>>(Wo, Wot, D_, D_);
        dim3 g1(FF_ / 32, D_ / 32, L_);
        transpose_conv_kernel<<<g1, 256, 0, stream>>>(W1, W1t, D_, FF_);
        dim3 g2(D_ / 32, FF_ / 32, L_);
        transpose_conv_kernel<<<g2, 256, 0, stream>>>(W2, W2t, FF_, D_);
        conv_bf16_kernel<<<(V_ * D_ + 255) / 256, 256, 0, stream>>>(emb, embb, V_ * D_);
    }

    embed_kernel<<<NTOK, 128, 0, stream>>>(tok, emb, PE, X, Xb);

    dim3 blk(256);
    dim3 gqkv(1536 / 128, NTOK / 128);      // 12 x 64 = 768 blocks, BM=128
    dim3 g512n(D_ / 128, NTOK / 64);        // 4 x 128 = 512 blocks, BM=64
    dim3 gff (FF_ / 128, NTOK / 128);       // 16 x 64 = 1024 blocks, BM=128
    dim3 gout(V_ / 128, NTOK / 64);         // 2 x 128 = 256 blocks, BM=64
    dim3 gattn(S_ / 128, H_, B_);           // paired q-tiles: 16 x 8 x 4 = 512
    dim3 gln(NTOK / 4);

    for (int l = 0; l < L_; ++l) {
        const __hip_bfloat16* wqkv = Wqkvt + (size_t)l * 1536 * D_;
        const __hip_bfloat16* wot = Wot + (size_t)l * D_ * D_;
        const __hip_bfloat16* w1t = W1t + (size_t)l * D_ * FF_;
        const __hip_bfloat16* w2t = W2t + (size_t)l * FF_ * D_;

        gemm_bf16_kernel<128, 0, 4><<<gqkv, blk, 0, stream>>>(
            Xb, wqkv, bq + l * D_, bk + l * D_, bv + l * D_,
            nullptr, Qb, Kb, Vb, VTb, NTOK, 1536, D_);

        attn_mfma_kernel<<<gattn, blk, 0, stream>>>(Qb, Kb, Vb, VTb, Ob);

        gemm_bf16_kernel<64, 0, 1><<<g512n, blk, 0, stream>>>(
            Ob, wot, bo + l * D_, nullptr, nullptr,
            nullptr, Tb, nullptr, nullptr, nullptr, NTOK, D_, D_);
        add_ln_kernel<<<gln, blk, 0, stream>>>(X, Tb, ln1g + l * D_, ln1b + l * D_, Xb);

        gemm_bf16_kernel<128, 1, 1><<<gff, blk, 0, stream>>>(
            Xb, w1t, b1 + l * FF_, nullptr, nullptr,
            nullptr, Hb, nullptr, nullptr, nullptr, NTOK, FF_, D_);
        gemm_bf16_kernel<64, 0, 1><<<g512n, blk, 0, stream>>>(
            Hb, w2t, b2 + l * D_, nullptr, nullptr,
            nullptr, Tb, nullptr, nullptr, nullptr, NTOK, D_, FF_);
        add_ln_kernel<<<gln, blk, 0, stream>>>(X, Tb, ln2g + l * D_, ln2b + l * D_, Xb);
    }

    gemm_bf16_kernel<64, 0, 0><<<gout, blk, 0, stream>>>(
        Xb, embb, b_out, nullptr, nullptr,
        out, nullptr, nullptr, nullptr, nullptr, NTOK, V_, D_);
}

// Round 8
// 651.915 us; speedup vs baseline: 1.1576x; 1.1576x over previous
//
#include <hip/hip_runtime.h>
#include <hip/hip_bf16.h>
#include <math.h>

// Problem constants
#define B_  4
#define S_  2048
#define D_  512
#define H_  8
#define DH_ 64
#define FF_ 2048
#define L_  4
#define V_  256
#define NTOK (B_ * S_)          // 8192
#define XN  ((size_t)NTOK * D_) // 4,194,304 elems per [B,S,D] buffer

typedef __attribute__((ext_vector_type(8))) short bf16x8;
typedef __attribute__((ext_vector_type(4))) float f32x4;
typedef __attribute__((ext_vector_type(8))) unsigned short u16x8;
typedef __attribute__((ext_vector_type(4))) unsigned short u16x4;

typedef const __attribute__((address_space(1))) unsigned int* gptr_u32;
typedef __attribute__((address_space(3))) unsigned int* lptr_u32;

__device__ __forceinline__ float bf2f(unsigned short u) {
    return __uint_as_float((unsigned)u << 16);
}
__device__ __forceinline__ unsigned short f2bf_bits(float f) {
    __hip_bfloat16 t = __float2bfloat16(f);
    return *(unsigned short*)&t;
}

// ---------------------------------------------------------------------------
// Positional-encoding table: PE[s][d], computed once per launch.
// ---------------------------------------------------------------------------
__global__ void pe_table_kernel(float* __restrict__ PE) {
    int s = blockIdx.x;
    int d = threadIdx.x * 2;              // 256 threads -> d = 0,2,...,510
    float ang = (float)s * expf((float)d * (-logf(10000.0f) / (float)D_));
    PE[(size_t)s * D_ + d]     = sinf(ang);
    PE[(size_t)s * D_ + d + 1] = cosf(ang);
}

// ---------------------------------------------------------------------------
// Embedding + PE lookup -> X fp32 and Xb bf16. grid NTOK, 128 threads.
// ---------------------------------------------------------------------------
__global__ void embed_kernel(const int* __restrict__ tok,
                             const float* __restrict__ emb,
                             const float* __restrict__ PE,
                             float* __restrict__ X,
                             __hip_bfloat16* __restrict__ Xb) {
    int bs = blockIdx.x;
    int s = bs % S_;
    int t = tok[bs];
    const float scale = 22.62741699796952f; // sqrt(512)
    int d = threadIdx.x * 4;
    float4 e = *(const float4*)(emb + (size_t)t * D_ + d);
    float4 p = *(const float4*)(PE + (size_t)s * D_ + d);
    float4 v = make_float4(e.x * scale + p.x, e.y * scale + p.y,
                           e.z * scale + p.z, e.w * scale + p.w);
    *(float4*)(X + (size_t)bs * D_ + d) = v;
    u16x4 pk = { f2bf_bits(v.x), f2bf_bits(v.y), f2bf_bits(v.z), f2bf_bits(v.w) };
    *(u16x4*)((unsigned short*)Xb + (size_t)bs * D_ + d) = pk;
}

// ---------------------------------------------------------------------------
// Weight prep
// ---------------------------------------------------------------------------
__global__ void transpose_conv_kernel(const float* __restrict__ W,
                                      __hip_bfloat16* __restrict__ Wt,
                                      int K, int N) {
    const float* Wl = W + (size_t)blockIdx.z * K * N;
    __hip_bfloat16* Wtl = Wt + (size_t)blockIdx.z * K * N;
    __shared__ float t[32][33];
    int k0 = blockIdx.y * 32, n0 = blockIdx.x * 32;
    int tx = threadIdx.x & 31, ty = threadIdx.x >> 5;
    #pragma unroll
    for (int q = 0; q < 4; ++q)
        t[ty + q * 8][tx] = Wl[(size_t)(k0 + ty + q * 8) * N + n0 + tx];
    __syncthreads();
    #pragma unroll
    for (int q = 0; q < 4; ++q)
        Wtl[(size_t)(n0 + ty + q * 8) * K + k0 + tx] =
            __float2bfloat16(t[tx][ty + q * 8]);
}

// QKV fused: dst[l][1536][512], rows 0-511 Wq^T, 512-1023 Wk^T, 1024-1535 Wv^T
__global__ void transpose_qkv_kernel(const float* __restrict__ Wq,
                                     const float* __restrict__ Wk,
                                     const float* __restrict__ Wv,
                                     __hip_bfloat16* __restrict__ dst) {
    int z = blockIdx.z, l = z / 3, which = z % 3;
    const float* src = (which == 0 ? Wq : which == 1 ? Wk : Wv) + (size_t)l * D_ * D_;
    __hip_bfloat16* d = dst + (size_t)l * 1536 * D_ + (size_t)which * D_ * D_;
    __shared__ float t[32][33];
    int k0 = blockIdx.y * 32, n0 = blockIdx.x * 32;
    int tx = threadIdx.x & 31, ty = threadIdx.x >> 5;
    #pragma unroll
    for (int q = 0; q < 4; ++q)
        t[ty + q * 8][tx] = src[(size_t)(k0 + ty + q * 8) * D_ + n0 + tx];
    __syncthreads();
    #pragma unroll
    for (int q = 0; q < 4; ++q)
        d[(size_t)(n0 + ty + q * 8) * D_ + k0 + tx] =
            __float2bfloat16(t[tx][ty + q * 8]);
}

__global__ void conv_bf16_kernel(const float* __restrict__ in,
                                 __hip_bfloat16* __restrict__ out, int n) {
    int i = blockIdx.x * 256 + threadIdx.x;
    if (i < n) out[i] = __float2bfloat16(in[i]);
}

// ---------------------------------------------------------------------------
// bf16 MFMA GEMM, double-buffered: C = A[M,K] @ Bt[N,K]^T + bias
// BM = 128 or 64. BN=128, BK=32. Counted vmcnt keeps next tile's
// global_load_lds in flight across the barrier.
// OUT_MODE: 0 = fp32 [M,N]; 1 = bf16 [M,N]; 4 = QKV fused (N=1536)
// ---------------------------------------------------------------------------
template <int BM, int RELU, int OUT_MODE>
__global__ __launch_bounds__(256)
void gemm_bf16_kernel(const __hip_bfloat16* __restrict__ A,
                      const __hip_bfloat16* __restrict__ Bt,
                      const float* __restrict__ bias0,
                      const float* __restrict__ bias1,
                      const float* __restrict__ bias2,
                      float* __restrict__ Cf,
                      __hip_bfloat16* __restrict__ Cb0,
                      __hip_bfloat16* __restrict__ Cb1,
                      __hip_bfloat16* __restrict__ Cb2,
                      __hip_bfloat16* __restrict__ CbT,
                      int M, int N, int K) {
    constexpr int MI = BM / 32;              // M-fragments per wave
    __shared__ unsigned short As[2][BM * 32];
    __shared__ unsigned short Bs[2][128 * 32];
    int tid = threadIdx.x;
    int lane = tid & 63, wid = tid >> 6;
    int wm = (wid >> 1) * (BM / 2), wn = (wid & 1) * 64;
    int g = lane >> 4, il = lane & 15;

    // XCD-aware swizzle: contiguous chunk of flat ids per XCD (grid % 8 == 0)
    int gx = gridDim.x;
    int fid = blockIdx.x + gx * blockIdx.y;
    int cpx = (gx * gridDim.y) >> 3;
    int swz = (fid & 7) * cpx + (fid >> 3);
    int m0 = (swz / gx) * BM, n0 = (swz % gx) * 128;

    auto stage = [&](int buf, int k0) {
        #pragma unroll
        for (int q = 0; q < BM / 64; ++q) {
            int idx = q * 256 + tid;
            int r = idx >> 2, c = idx & 3;
            int csw = (c ^ r) & 3;
            const __hip_bfloat16* sa = A + (size_t)(m0 + r) * K + k0 + csw * 8;
            __builtin_amdgcn_global_load_lds((gptr_u32)(const void*)sa,
                                             (lptr_u32)(void*)&As[buf][idx * 8], 16, 0, 0);
        }
        #pragma unroll
        for (int q = 0; q < 2; ++q) {
            int idx = q * 256 + tid;
            int r = idx >> 2, c = idx & 3;
            int csw = (c ^ r) & 3;
            const __hip_bfloat16* sb = Bt + (size_t)(n0 + r) * K + k0 + csw * 8;
            __builtin_amdgcn_global_load_lds((gptr_u32)(const void*)sb,
                                             (lptr_u32)(void*)&Bs[buf][idx * 8], 16, 0, 0);
        }
    };

    f32x4 acc[MI][4] = {};
    int NT = K >> 5;
    stage(0, 0);

    for (int t = 0; t < NT; ++t) {
        int cur = t & 1;
        if (t + 1 < NT) {
            stage(cur ^ 1, (t + 1) << 5);
            if constexpr (BM == 128)
                asm volatile("s_waitcnt vmcnt(4)" ::: "memory");
            else
                asm volatile("s_waitcnt vmcnt(3)" ::: "memory");
        } else {
            asm volatile("s_waitcnt vmcnt(0)" ::: "memory");
        }
        __builtin_amdgcn_s_barrier();

        bf16x8 af[MI], bf[4];
        #pragma unroll
        for (int i = 0; i < MI; ++i) {
            int m = wm + i * 16 + il;
            af[i] = *(const bf16x8*)&As[cur][m * 32 + ((g ^ m) & 3) * 8];
        }
        #pragma unroll
        for (int j = 0; j < 4; ++j) {
            int n = wn + j * 16 + il;
            bf[j] = *(const bf16x8*)&Bs[cur][n * 32 + ((g ^ n) & 3) * 8];
        }
        #pragma unroll
        for (int i = 0; i < MI; ++i)
            #pragma unroll
            for (int j = 0; j < 4; ++j)
                acc[i][j] = __builtin_amdgcn_mfma_f32_16x16x32_bf16(
                    af[i], bf[j], acc[i][j], 0, 0, 0);

        __builtin_amdgcn_s_barrier();   // all waves done reading before overwrite
    }

    // C/D layout: col = lane&15, row = (lane>>4)*4 + reg
    if constexpr (OUT_MODE == 4) {
        int seg = n0 >> 9;                       // block-uniform
        const float* bias = seg == 0 ? bias0 : seg == 1 ? bias1 : bias2;
        __hip_bfloat16* Crow = seg == 0 ? Cb0 : seg == 1 ? Cb1 : Cb2;
        int nseg = n0 & 511;
        #pragma unroll
        for (int j = 0; j < 4; ++j) {
            int coll = nseg + wn + j * 16 + il;
            float bv = bias[coll];
            #pragma unroll
            for (int i = 0; i < MI; ++i) {
                int row0 = m0 + wm + i * 16 + g * 4;
                if (seg < 2) {
                    #pragma unroll
                    for (int r = 0; r < 4; ++r)
                        Crow[(size_t)(row0 + r) * 512 + coll] =
                            __float2bfloat16(acc[i][j][r] + bv);
                } else {
                    u16x4 pk;
                    #pragma unroll
                    for (int r = 0; r < 4; ++r) {
                        float v = acc[i][j][r] + bv;
                        Crow[(size_t)(row0 + r) * 512 + coll] = __float2bfloat16(v);
                        pk[r] = f2bf_bits(v);
                    }
                    int hh = coll >> 6, dh = coll & 63;
                    int bb = row0 >> 11, s0 = row0 & 2047;
                    *(u16x4*)(CbT + ((size_t)((bb * 8 + hh) * 64 + dh) * 2048 + s0)) = pk;
                }
            }
        }
    } else {
        #pragma unroll
        for (int j = 0; j < 4; ++j) {
            int col = n0 + wn + j * 16 + il;
            float bv = bias0[col];
            #pragma unroll
            for (int i = 0; i < MI; ++i) {
                #pragma unroll
                for (int r = 0; r < 4; ++r) {
                    int row = m0 + wm + i * 16 + g * 4 + r;
                    float v = acc[i][j][r] + bv;
                    if (RELU) v = fmaxf(v, 0.0f);
                    if (OUT_MODE == 1) Cb0[(size_t)row * N + col] = __float2bfloat16(v);
                    else               Cf[(size_t)row * N + col] = v;
                }
            }
        }
    }
}

// ---------------------------------------------------------------------------
// MFMA block-sparse flash attention (v5 = round-6 v3 + balanced dispatch).
// One q-tile per block, grid 1024. Within each XCD, qt varies SLOWEST in
// arrival order -> CU c gets qt in {c/4, c/4+8, c/4+16, c/4+24} (4 groups),
// per-CU work spread ~1.26:1 instead of 6:1. (b,h) clustering per XCD kept.
// ---------------------------------------------------------------------------
__device__ __forceinline__ bf16x8 lds_frag(const unsigned short* base, int row, int chunk) {
    int byte = (row << 7) + (((chunk ^ (row & 7)) & 7) << 4);
    return *(const bf16x8*)((const char*)base + byte);
}

__global__ __launch_bounds__(256)
void attn_mfma_kernel(const __hip_bfloat16* __restrict__ Q,   // [NTOK][512]
                      const __hip_bfloat16* __restrict__ K,   // [NTOK][512]
                      const __hip_bfloat16* __restrict__ V,   // [NTOK][512]
                      const __hip_bfloat16* __restrict__ VT,  // [B*H*64][2048]
                      __hip_bfloat16* __restrict__ O) {       // [NTOK][512]
    __shared__ unsigned short Ks[2][64 * 64];
    __shared__ unsigned short Vs[2][64 * 64];
    __shared__ unsigned short Ps[4][16 * 64];

    // balanced dispatch: xcd = d&7 (HW round-robin); within XCD, gsub fast,
    // qt slowest -> consecutive arrivals on an XCD sweep groups, then qt.
    int d = blockIdx.x + 32 * (blockIdx.y + 8 * blockIdx.z);  // 0..1023
    int xcd = d & 7;
    int rest = d >> 3;          // 0..127
    int gsub = rest & 3;        // 4 (b,h) groups per XCD
    int qt = rest >> 2;         // 0..31, slowest
    int grp = xcd * 4 + gsub;   // 0..31
    int h = grp & 7, b = grp >> 3;
    int i0 = qt * 64;

    int tid = threadIdx.x, lane = tid & 63, wv = tid >> 6;
    int g = lane >> 4, il = lane & 15, g4 = g * 4;

    int nloc = min(i0 >> 6, 4) + 1;
    int add0 = (i0 > 256);
    int nt = nloc + add0;

    const size_t vt_off = (size_t)((b * 8 + h) * 64) * 2048;
    auto j0_of = [&](int t) { return (t < nloc) ? (i0 - 64 * t) : 0; };

    auto stage = [&](int buf, int j0) {
        #pragma unroll
        for (int q = 0; q < 2; ++q) {
            int idx = q * 256 + tid;
            int row = idx >> 3, c = idx & 7;
            int csw = c ^ (row & 7);
            const __hip_bfloat16* sk = K + (size_t)(b * 2048 + j0 + row) * 512 + h * 64 + csw * 8;
            __builtin_amdgcn_global_load_lds((gptr_u32)(const void*)sk,
                                             (lptr_u32)(void*)&Ks[buf][idx * 8], 16, 0, 0);
            const __hip_bfloat16* sv = VT + vt_off + (size_t)row * 2048 + j0 + csw * 8;
            __builtin_amdgcn_global_load_lds((gptr_u32)(const void*)sv,
                                             (lptr_u32)(void*)&Vs[buf][idx * 8], 16, 0, 0);
        }
    };

    int iq = i0 + wv * 16 + il;
    bf16x8 qf[2];
    #pragma unroll
    for (int kh = 0; kh < 2; ++kh)
        qf[kh] = *(const bf16x8*)(Q + (size_t)(b * 2048 + iq) * 512 + h * 64 + kh * 32 + g * 8);

    stage(0, j0_of(0));   // overlap first tile load with scalar phase

    float qfl[16];
    #pragma unroll
    for (int kh = 0; kh < 2; ++kh)
        #pragma unroll
        for (int e = 0; e < 8; ++e)
            qfl[kh * 8 + e] = bf2f(((u16x8)qf[kh])[e]);

    unsigned short* myP = Ps[wv];
    f32x4 o[4] = {};
    float os[16] = {};
    float m = -1e30f, l = 0.0f;
    const float CSC = 0.18033688011112042f; // 0.125 * log2(e)

    // ---- scalar strided phase ----
    const unsigned short* Kbase = (const unsigned short*)(K + (size_t)b * 2048 * 512 + h * 64);
    const unsigned short* Vbase = (const unsigned short*)(V + (size_t)b * 2048 * 512 + h * 64);
    for (int j = iq - 384; j >= 16; j -= 128) {
        const unsigned short* kr = Kbase + (size_t)j * 512;
        u16x8 k0 = *(const u16x8*)(kr + g * 8);
        u16x8 k1 = *(const u16x8*)(kr + 32 + g * 8);
        float dot = 0.0f;
        #pragma unroll
        for (int e = 0; e < 8; ++e)
            dot += qfl[e] * bf2f(k0[e]) + qfl[8 + e] * bf2f(k1[e]);
        dot += __shfl_xor(dot, 16);
        dot += __shfl_xor(dot, 32);
        float s2 = dot * CSC;
        float mn = fmaxf(m, s2);
        float al = exp2f(m - mn);
        float p = exp2f(s2 - mn);
        l = l * al + p;
        m = mn;
        const unsigned short* vr = Vbase + (size_t)j * 512;
        u16x8 v0 = *(const u16x8*)(vr + g * 8);
        u16x8 v1 = *(const u16x8*)(vr + 32 + g * 8);
        #pragma unroll
        for (int e = 0; e < 8; ++e) {
            os[e]     = os[e]     * al + p * bf2f(v0[e]);
            os[8 + e] = os[8 + e] * al + p * bf2f(v1[e]);
        }
    }

    // ---- MFMA tile phase ----
    for (int t = 0; t < nt; ++t) {
        __syncthreads();
        int cur = t & 1;
        if (t + 1 < nt) stage(cur ^ 1, j0_of(t + 1));
        int j0 = j0_of(t);
        bool gtile = (t >= nloc);
        bool dtile = (t == 0);

        f32x4 s[4] = {};
        __builtin_amdgcn_s_setprio(1);
        if (gtile) {
            #pragma unroll
            for (int kh = 0; kh < 2; ++kh) {
                bf16x8 a = lds_frag(Ks[cur], il, kh * 4 + g);
                s[0] = __builtin_amdgcn_mfma_f32_16x16x32_bf16(a, qf[kh], s[0], 0, 0, 0);
            }
        } else if (dtile) {
            #pragma unroll
            for (int kh = 0; kh < 2; ++kh)
                #pragma unroll
                for (int jn = 0; jn < 4; ++jn)
                    if (jn <= wv) {
                        bf16x8 a = lds_frag(Ks[cur], jn * 16 + il, kh * 4 + g);
                        s[jn] = __builtin_amdgcn_mfma_f32_16x16x32_bf16(a, qf[kh], s[jn], 0, 0, 0);
                    }
        } else {
            #pragma unroll
            for (int kh = 0; kh < 2; ++kh)
                #pragma unroll
                for (int jn = 0; jn < 4; ++jn) {
                    bf16x8 a = lds_frag(Ks[cur], jn * 16 + il, kh * 4 + g);
                    s[jn] = __builtin_amdgcn_mfma_f32_16x16x32_bf16(a, qf[kh], s[jn], 0, 0, 0);
                }
        }
        __builtin_amdgcn_s_setprio(0);

        // scale + mask + local max
        float mloc = -1e30f;
        if (gtile) {               // all 16 global keys allowed (iq >= 320 > 15)
            #pragma unroll
            for (int r = 0; r < 4; ++r) {
                float sv = s[0][r] * CSC;
                s[0][r] = sv;
                mloc = fmaxf(mloc, sv);
            }
        } else if (dtile) {        // diagonal: jn<wv all pass, jn==wv causal mask
            #pragma unroll
            for (int jn = 0; jn < 4; ++jn) {
                if (jn < wv) {
                    #pragma unroll
                    for (int r = 0; r < 4; ++r) {
                        float sv = s[jn][r] * CSC;
                        s[jn][r] = sv;
                        mloc = fmaxf(mloc, sv);
                    }
                } else if (jn == wv) {
                    #pragma unroll
                    for (int r = 0; r < 4; ++r) {
                        float sv = (g4 + r <= il) ? s[jn][r] * CSC : -1e30f;
                        s[jn][r] = sv;
                        mloc = fmaxf(mloc, sv);
                    }
                }
            }
        } else if (t == 4) {       // window edge: local | strided | global
            #pragma unroll
            for (int jn = 0; jn < 4; ++jn)
                #pragma unroll
                for (int r = 0; r < 4; ++r) {
                    int jg = j0 + jn * 16 + g4 + r;
                    int dij = iq - jg;
                    bool ok = (dij < 256) || ((dij & 127) == 0) || (jg < 16);
                    float sv = ok ? s[jn][r] * CSC : -1e30f;
                    s[jn][r] = sv;
                    mloc = fmaxf(mloc, sv);
                }
        } else {                   // fully inside window
            #pragma unroll
            for (int jn = 0; jn < 4; ++jn)
                #pragma unroll
                for (int r = 0; r < 4; ++r) {
                    float sv = s[jn][r] * CSC;
                    s[jn][r] = sv;
                    mloc = fmaxf(mloc, sv);
                }
        }
        mloc = fmaxf(mloc, __shfl_xor(mloc, 16));
        mloc = fmaxf(mloc, __shfl_xor(mloc, 32));
        float mn = fmaxf(m, mloc);
        float al = exp2f(m - mn);

        float lloc = 0.0f;
        if (gtile) {
            #pragma unroll
            for (int r = 0; r < 4; ++r) {
                float p = exp2f(s[0][r] - mn);
                s[0][r] = p;
                lloc += p;
            }
        } else {
            #pragma unroll
            for (int jn = 0; jn < 4; ++jn) {
                if (dtile && jn > wv) continue;
                #pragma unroll
                for (int r = 0; r < 4; ++r) {
                    float p = exp2f(s[jn][r] - mn);
                    s[jn][r] = p;
                    lloc += p;
                }
            }
        }
        lloc += __shfl_xor(lloc, 16);
        lloc += __shfl_xor(lloc, 32);
        l = l * al + lloc;
        m = mn;

        if (!__all(al == 1.0f)) {
            float ar[4];
            #pragma unroll
            for (int r = 0; r < 4; ++r) ar[r] = __shfl(al, g4 + r);
            #pragma unroll
            for (int dn = 0; dn < 4; ++dn)
                #pragma unroll
                for (int r = 0; r < 4; ++r) o[dn][r] *= ar[r];
            #pragma unroll
            for (int e = 0; e < 16; ++e) os[e] *= al;
        }

        // P -> LDS (gtile: jn0 data + jn1 zeros; dtile: zeros for jn>wv)
        #pragma unroll
        for (int jn = 0; jn < 4; ++jn) {
            if (gtile && jn >= 2) continue;
            u16x4 pk = { 0, 0, 0, 0 };
            bool live = gtile ? (jn == 0) : (!dtile || jn <= wv);
            if (live) {
                #pragma unroll
                for (int r = 0; r < 4; ++r) pk[r] = f2bf_bits(s[jn][r]);
            }
            int byte = ((il << 7) + (jn << 5) + (g << 3)) ^ ((il & 7) << 4);
            *(u16x4*)((char*)myP + byte) = pk;
        }
        int khmax = (gtile || (dtile && wv < 2)) ? 1 : 2;
        __builtin_amdgcn_s_setprio(1);
        #pragma unroll
        for (int kh = 0; kh < 2; ++kh) {
            if (kh < khmax) {
                bf16x8 pa = lds_frag(myP, il, kh * 4 + g);
                #pragma unroll
                for (int dn = 0; dn < 4; ++dn) {
                    bf16x8 bv = lds_frag(Vs[cur], dn * 16 + il, kh * 4 + g);
                    o[dn] = __builtin_amdgcn_mfma_f32_16x16x32_bf16(pa, bv, o[dn], 0, 0, 0);
                }
            }
        }
        __builtin_amdgcn_s_setprio(0);
    }

    // ---- epilogue: merge os (row=il, dim split by g) with o fragment ----
    __syncthreads();
    float* osl = (float*)&Ks[0][0] + wv * 1024;  // 16 rows x 64 dims per wave
    #pragma unroll
    for (int kh = 0; kh < 2; ++kh)
        #pragma unroll
        for (int e = 0; e < 8; ++e)
            osl[il * 64 + kh * 32 + g * 8 + e] = os[kh * 8 + e];
    __syncthreads();

    float li[4];
    #pragma unroll
    for (int r = 0; r < 4; ++r) li[r] = 1.0f / __shfl(l, g4 + r);
    #pragma unroll
    for (int dn = 0; dn < 4; ++dn)
        #pragma unroll
        for (int r = 0; r < 4; ++r) {
            int row = i0 + wv * 16 + g4 + r;
            float add = osl[(g4 + r) * 64 + dn * 16 + il];
            O[(size_t)(b * 2048 + row) * 512 + h * 64 + dn * 16 + il] =
                __float2bfloat16((o[dn][r] + add) * li[r]);
        }
}

// ---------------------------------------------------------------------------
// Fused residual add + LayerNorm, vectorized: 4 rows/block (4 waves)
// ---------------------------------------------------------------------------
__global__ __launch_bounds__(256)
void add_ln_kernel(float* __restrict__ X,
                   const __hip_bfloat16* __restrict__ T,
                   const float* __restrict__ g,
                   const float* __restrict__ bb,
                   __hip_bfloat16* __restrict__ Xb) {
    size_t row = blockIdx.x * 4 + (threadIdx.x >> 6);
    int lane = threadIdx.x & 63;
    int d0 = lane * 8;
    float4 x0 = *(const float4*)(X + row * D_ + d0);
    float4 x1 = *(const float4*)(X + row * D_ + d0 + 4);
    u16x8 tv = *(const u16x8*)((const unsigned short*)T + row * D_ + d0);
    float v[8] = { x0.x + bf2f(tv[0]), x0.y + bf2f(tv[1]),
                   x0.z + bf2f(tv[2]), x0.w + bf2f(tv[3]),
                   x1.x + bf2f(tv[4]), x1.y + bf2f(tv[5]),
                   x1.z + bf2f(tv[6]), x1.w + bf2f(tv[7]) };
    float sum = 0.0f;
    #pragma unroll
    for (int q = 0; q < 8; ++q) sum += v[q];
    #pragma unroll
    for (int o = 32; o; o >>= 1) sum += __shfl_xor(sum, o);
    float mean = sum * (1.0f / D_);
    float var = 0.0f;
    #pragma unroll
    for (int q = 0; q < 8; ++q) { float dd = v[q] - mean; var += dd * dd; }
    #pragma unroll
    for (int o = 32; o; o >>= 1) var += __shfl_xor(var, o);
    var *= (1.0f / D_);
    float r = rsqrtf(var + 1e-5f);
    float4 g0 = *(const float4*)(g + d0),  g1 = *(const float4*)(g + d0 + 4);
    float4 b0 = *(const float4*)(bb + d0), b1 = *(const float4*)(bb + d0 + 4);
    float y[8];
    y[0] = (v[0]-mean)*r*g0.x+b0.x; y[1] = (v[1]-mean)*r*g0.y+b0.y;
    y[2] = (v[2]-mean)*r*g0.z+b0.z; y[3] = (v[3]-mean)*r*g0.w+b0.w;
    y[4] = (v[4]-mean)*r*g1.x+b1.x; y[5] = (v[5]-mean)*r*g1.y+b1.y;
    y[6] = (v[6]-mean)*r*g1.z+b1.z; y[7] = (v[7]-mean)*r*g1.w+b1.w;
    *(float4*)(X + row * D_ + d0)     = make_float4(y[0], y[1], y[2], y[3]);
    *(float4*)(X + row * D_ + d0 + 4) = make_float4(y[4], y[5], y[6], y[7]);
    u16x8 pk;
    #pragma unroll
    for (int q = 0; q < 8; ++q) pk[q] = f2bf_bits(y[q]);
    *(u16x8*)((unsigned short*)Xb + row * D_ + d0) = pk;
}

// ---------------------------------------------------------------------------
extern "C" void kernel_launch(void* const* d_in, const int* in_sizes, int n_in,
                              void* d_out, int out_size, void* d_ws, size_t ws_size,
                              hipStream_t stream) {
    const int*   tok   = (const int*)  d_in[0];
    const float* emb   = (const float*)d_in[1];
    const float* b_out = (const float*)d_in[2];
    const float* Wq    = (const float*)d_in[3];
    const float* bq    = (const float*)d_in[4];
    const float* Wk    = (const float*)d_in[5];
    const float* bk    = (const float*)d_in[6];
    const float* Wv    = (const float*)d_in[7];
    const float* bv    = (const float*)d_in[8];
    const float* Wo    = (const float*)d_in[9];
    const float* bo    = (const float*)d_in[10];
    const float* ln1g  = (const float*)d_in[11];
    const float* ln1b  = (const float*)d_in[12];
    const float* W1    = (const float*)d_in[13];
    const float* b1    = (const float*)d_in[14];
    const float* W2    = (const float*)d_in[15];
    const float* b2    = (const float*)d_in[16];
    const float* ln2g  = (const float*)d_in[17];
    const float* ln2b  = (const float*)d_in[18];
    float* out = (float*)d_out;

    char* w = (char*)d_ws;
    auto alloc = [&](size_t bytes) {
        char* p = w;
        w += (bytes + 255) & ~(size_t)255;
        return p;
    };
    float*          X   = (float*)         alloc(XN * 4);
    __hip_bfloat16* Xb  = (__hip_bfloat16*)alloc(XN * 2);
    __hip_bfloat16* Tb  = (__hip_bfloat16*)alloc(XN * 2);
    char* uni = alloc(XN * 2 * 5);
    __hip_bfloat16* Qb  = (__hip_bfloat16*)uni;
    __hip_bfloat16* Kb  = Qb + XN;
    __hip_bfloat16* Vb  = Kb + XN;
    __hip_bfloat16* VTb = Vb + XN;   // [B,H,64,S]
    __hip_bfloat16* Ob  = VTb + XN;
    __hip_bfloat16* Hb  = (__hip_bfloat16*)uni;      // [NTOK, FF] (reuses Qb..VTb)
    __hip_bfloat16* Wqkvt = (__hip_bfloat16*)alloc((size_t)L_ * 1536 * D_ * 2);
    __hip_bfloat16* Wot  = (__hip_bfloat16*)alloc((size_t)L_ * D_ * D_ * 2);
    __hip_bfloat16* W1t  = (__hip_bfloat16*)alloc((size_t)L_ * D_ * FF_ * 2);
    __hip_bfloat16* W2t  = (__hip_bfloat16*)alloc((size_t)L_ * FF_ * D_ * 2);
    __hip_bfloat16* embb = (__hip_bfloat16*)alloc((size_t)V_ * D_ * 2);
    float*          PE   = (float*)alloc((size_t)S_ * D_ * 4);

    // ---- prep ----
    {
        pe_table_kernel<<<S_, 256, 0, stream>>>(PE);
        dim3 gqkv(D_ / 32, D_ / 32, L_ * 3);
        transpose_qkv_kernel<<<gqkv, 256, 0, stream>>>(Wq, Wk, Wv, Wqkvt);
        dim3 gdd(D_ / 32, D_ / 32, L_);
        transpose_conv_kernel<<<gdd, 256, 0, stream>>>(Wo, Wot, D_, D_);
        dim3 g1(FF_ / 32, D_ / 32, L_);
        transpose_conv_kernel<<<g1, 256, 0, stream>>>(W1, W1t, D_, FF_);
        dim3 g2(D_ / 32, FF_ / 32, L_);
        transpose_conv_kernel<<<g2, 256, 0, stream>>>(W2, W2t, FF_, D_);
        conv_bf16_kernel<<<(V_ * D_ + 255) / 256, 256, 0, stream>>>(emb, embb, V_ * D_);
    }

    embed_kernel<<<NTOK, 128, 0, stream>>>(tok, emb, PE, X, Xb);

    dim3 blk(256);
    dim3 gqkv(1536 / 128, NTOK / 128);      // 12 x 64 = 768 blocks, BM=128
    dim3 g512n(D_ / 128, NTOK / 64);        // 4 x 128 = 512 blocks, BM=64
    dim3 gff (FF_ / 128, NTOK / 128);       // 16 x 64 = 1024 blocks, BM=128
    dim3 gout(V_ / 128, NTOK / 64);         // 2 x 128 = 256 blocks, BM=64
    dim3 gattn(S_ / 64, H_, B_);            // 32 x 8 x 4 = 1024
    dim3 gln(NTOK / 4);

    for (int l = 0; l < L_; ++l) {
        const __hip_bfloat16* wqkv = Wqkvt + (size_t)l * 1536 * D_;
        const __hip_bfloat16* wot = Wot + (size_t)l * D_ * D_;
        const __hip_bfloat16* w1t = W1t + (size_t)l * D_ * FF_;
        const __hip_bfloat16* w2t = W2t + (size_t)l * FF_ * D_;

        gemm_bf16_kernel<128, 0, 4><<<gqkv, blk, 0, stream>>>(
            Xb, wqkv, bq + l * D_, bk + l * D_, bv + l * D_,
            nullptr, Qb, Kb, Vb, VTb, NTOK, 1536, D_);

        attn_mfma_kernel<<<gattn, blk, 0, stream>>>(Qb, Kb, Vb, VTb, Ob);

        gemm_bf16_kernel<64, 0, 1><<<g512n, blk, 0, stream>>>(
            Ob, wot, bo + l * D_, nullptr, nullptr,
            nullptr, Tb, nullptr, nullptr, nullptr, NTOK, D_, D_);
        add_ln_kernel<<<gln, blk, 0, stream>>>(X, Tb, ln1g + l * D_, ln1b + l * D_, Xb);

        gemm_bf16_kernel<128, 1, 1><<<gff, blk, 0, stream>>>(
            Xb, w1t, b1 + l * FF_, nullptr, nullptr,
            nullptr, Hb, nullptr, nullptr, nullptr, NTOK, FF_, D_);
        gemm_bf16_kernel<64, 0, 1><<<g512n, blk, 0, stream>>>(
            Hb, w2t, b2 + l * D_, nullptr, nullptr,
            nullptr, Tb, nullptr, nullptr, nullptr, NTOK, D_, FF_);
        add_ln_kernel<<<gln, blk, 0, stream>>>(X, Tb, ln2g + l * D_, ln2b + l * D_, Xb);
    }

    gemm_bf16_kernel<64, 0, 0><<<gout, blk, 0, stream>>>(
        Xb, embb, b_out, nullptr, nullptr,
        out, nullptr, nullptr, nullptr, nullptr, NTOK, V_, D_);
}